// Round 8
// baseline (1121.681 us; speedup 1.0000x reference)
//
#include <hip/hip_runtime.h>
#include <hip/hip_bf16.h>
#include <hip/hip_fp16.h>

#define N_NODES   100000
#define N_EDGES   3200000
#define N_FEAT    500
#define HIDDEN    128
#define N_CLASSES 64
#define K_LAYERS  10
#define NBUCK     98          // ceil(N_NODES / 1024)

typedef __attribute__((ext_vector_type(8))) short bf16x8;
typedef __attribute__((ext_vector_type(4))) float f32x4;

__device__ inline ushort f2bf_rn(float f) {
  unsigned u = __float_as_uint(f);
  unsigned r = (u + 0x7FFFu + ((u >> 16) & 1u)) >> 16;
  return (ushort)r;
}
__device__ inline float bf2f(ushort h) {
  return __uint_as_float(((unsigned)h) << 16);
}
__device__ inline float2 h2f2(unsigned u) {
  __half2 h = *(__half2*)&u;
  return make_float2(__low2float(h), __high2float(h));
}
__device__ inline unsigned f2h2(float a, float b) {
  __half2 h = __floats2half2_rn(a, b);
  return *(unsigned*)&h;
}

// ============ CSR build via bucketed counting sort (no global scatter) ======
// Records packed as src | (dstLocal<<17); src < 2^17, dstLocal < 1024.

__global__ __launch_bounds__(256) void bucket_count_k(const int* __restrict__ dst,
                                                      int* __restrict__ bucket_cnt) {
  __shared__ int h[128];
  int t = threadIdx.x;
  if (t < 128) h[t] = 0;
  __syncthreads();
  for (int e = blockIdx.x * 256 + t; e < N_EDGES; e += gridDim.x * 256)
    atomicAdd(&h[dst[e] >> 10], 1);
  __syncthreads();
  if (t < 128 && h[t]) atomicAdd(&bucket_cnt[t], h[t]);
}

__global__ __launch_bounds__(128) void bucket_scan_k(const int* __restrict__ bucket_cnt,
                                                     int* __restrict__ bucket_base,
                                                     int* __restrict__ bcur,
                                                     int* __restrict__ offs) {
  __shared__ int sm[128];
  int t = threadIdx.x;
  int c = bucket_cnt[t];
  sm[t] = c;
  __syncthreads();
  for (int d = 1; d < 128; d <<= 1) {
    int v = (t >= d) ? sm[t - d] : 0;
    __syncthreads();
    sm[t] += v;
    __syncthreads();
  }
  int ex = sm[t] - c;  // exclusive prefix
  bucket_base[t] = ex;
  bcur[t] = ex;
  if (t == 127) bucket_base[128] = ex + c;  // == N_EDGES
  if (t == 0) offs[N_NODES] = N_EDGES;
}

#define BIN_CHUNK 12800   // 250 blocks * 12800 = 3.2M exactly
__global__ __launch_bounds__(256) void bin_scatter_k(const int* __restrict__ src,
                                                     const int* __restrict__ dst,
                                                     int* __restrict__ bcur,
                                                     int* __restrict__ binned) {
  __shared__ int h[128];
  __shared__ int hbase[128];
  int t = threadIdx.x;
  int e0 = blockIdx.x * BIN_CHUNK;
  int e1 = min(e0 + BIN_CHUNK, N_EDGES);
  if (t < 128) h[t] = 0;
  __syncthreads();
  for (int e = e0 + t; e < e1; e += 256) atomicAdd(&h[dst[e] >> 10], 1);
  __syncthreads();
  if (t < 128) {
    int c = h[t];
    hbase[t] = c ? atomicAdd(&bcur[t], c) : 0;
  }
  __syncthreads();
  if (t < 128) h[t] = 0;
  __syncthreads();
  for (int e = e0 + t; e < e1; e += 256) {
    int d = dst[e];
    int b = d >> 10;
    int pos = hbase[b] + atomicAdd(&h[b], 1);
    binned[pos] = (src[e] & 0x1FFFF) | ((d & 1023) << 17);
  }
}

__global__ __launch_bounds__(256) void bucket_fill_k(const int* __restrict__ binned,
                                                     const int* __restrict__ bucket_base,
                                                     int* __restrict__ offs,
                                                     float* __restrict__ dinv,
                                                     int* __restrict__ csr4) {
  __shared__ int cnt[1024];
  __shared__ int tsum[256];
  int b = blockIdx.x;
  int base = bucket_base[b];
  int nE = bucket_base[b + 1] - base;
  int node0 = b << 10;
  int nN = min(1024, N_NODES - node0);
  int t = threadIdx.x;
  #pragma unroll
  for (int i = 0; i < 4; ++i) cnt[t + i * 256] = 0;
  __syncthreads();
  for (int i = t; i < nE; i += 256) atomicAdd(&cnt[binned[base + i] >> 17], 1);
  __syncthreads();
  int c0 = cnt[4 * t], c1 = cnt[4 * t + 1], c2 = cnt[4 * t + 2], c3 = cnt[4 * t + 3];
  int s = c0 + c1 + c2 + c3;
  tsum[t] = s;
  __syncthreads();
  for (int d = 1; d < 256; d <<= 1) {
    int v = (t >= d) ? tsum[t - d] : 0;
    __syncthreads();
    tsum[t] += v;
    __syncthreads();
  }
  int run = tsum[t] - s;  // exclusive
  int p0 = run, p1 = run + c0, p2 = p1 + c1, p3 = p2 + c2;
  if (4 * t + 0 < nN) { offs[node0 + 4 * t + 0] = base + p0; dinv[node0 + 4 * t + 0] = rsqrtf(c0 + 1.f); }
  if (4 * t + 1 < nN) { offs[node0 + 4 * t + 1] = base + p1; dinv[node0 + 4 * t + 1] = rsqrtf(c1 + 1.f); }
  if (4 * t + 2 < nN) { offs[node0 + 4 * t + 2] = base + p2; dinv[node0 + 4 * t + 2] = rsqrtf(c2 + 1.f); }
  if (4 * t + 3 < nN) { offs[node0 + 4 * t + 3] = base + p3; dinv[node0 + 4 * t + 3] = rsqrtf(c3 + 1.f); }
  __syncthreads();
  cnt[4 * t] = p0; cnt[4 * t + 1] = p1; cnt[4 * t + 2] = p2; cnt[4 * t + 3] = p3;
  __syncthreads();
  for (int i = t; i < nE; i += 256) {
    int rec = binned[base + i];
    int p = base + atomicAdd(&cnt[rec >> 17], 1);
    csr4[p] = rec & 0x1FFFF;
  }
}

// ---------------- W^T bf16 hi/lo prep: W[K][N] -> WT[N][KPAD] ----------------
__global__ void prep_wt_k(const float* __restrict__ W, ushort* __restrict__ hi,
                          ushort* __restrict__ lo, int K, int N, int KPAD) {
  int idx = blockIdx.x * 256 + threadIdx.x;
  if (idx >= N * KPAD) return;
  int n = idx / KPAD, k = idx - n * KPAD;
  float v = (k < K) ? W[(size_t)k * N + n] : 0.f;
  ushort h = f2bf_rn(v);
  ushort l = f2bf_rn(v - bf2f(h));
  hi[idx] = h;
  lo[idx] = l;
}

// ---------------- split-bf16 MFMA GEMM with reg-prefetch pipeline ----------
// C[M x BN] = A[M x KTOT] @ B + bias. Block: 4 waves (2x2), tile 128 x BN,
// K-step 64, single LDS buffer. Global loads for step s+1 are issued BEFORE
// the MFMA phase of step s (T14 async-STAGE split): HBM latency hides under
// the 96-MFMA phase; ds_writes commit after the post-MFMA barrier.
template<int BN, int KTOT, int KPAD, bool RELU>
__global__ __launch_bounds__(256, 2) void mfma_gemm_k(
    const float* __restrict__ A, const ushort* __restrict__ BThi,
    const ushort* __restrict__ BTlo, const float* __restrict__ bias,
    float* __restrict__ C, int M) {
  constexpr int BK = 64;
  constexpr int NF = BN / 32;        // n-frags per wave
  constexpr int NB = BN * 8 / 256;   // B stage chunks per thread
  constexpr int NS = KPAD / BK;      // K-steps
  __shared__ __align__(16) ushort sm[(2 * 128 + 2 * BN) * BK];
  ushort* Ahi = sm;
  ushort* Alo = sm + 128 * BK;
  ushort* Bhi = sm + 2 * 128 * BK;
  ushort* Blo = Bhi + BN * BK;

  int tid = threadIdx.x;
  int lane = tid & 63, wid = tid >> 6;
  int wm = wid >> 1, wn = wid & 1;
  int lrow = lane & 15, lg = lane >> 4;
  int row0 = blockIdx.x * 128;

  f32x4 acc[4][NF];
  #pragma unroll
  for (int m = 0; m < 4; ++m)
    #pragma unroll
    for (int n = 0; n < NF; ++n) acc[m][n] = (f32x4){0.f, 0.f, 0.f, 0.f};

  float4 aR[8];
  uint4 bhR[NB], blR[NB];

  auto load_st = [&](int kc) {
    #pragma unroll
    for (int i = 0; i < 8; ++i) {
      int c = tid + i * 256;               // 0..2047 (128 rows x 16 float4)
      int r = c >> 4, k4 = (c & 15) << 2;
      int gr = row0 + r, gk = kc + k4;
      float4 v = make_float4(0.f, 0.f, 0.f, 0.f);
      if (gr < M) {
        if (gk + 3 < KTOT) {
          v = *(const float4*)(A + (size_t)gr * KTOT + gk);
        } else {
          float* vp = &v.x;
          #pragma unroll
          for (int e = 0; e < 4; ++e)
            if (gk + e < KTOT) vp[e] = A[(size_t)gr * KTOT + gk + e];
        }
      }
      aR[i] = v;
    }
    #pragma unroll
    for (int i = 0; i < NB; ++i) {
      int c = tid + i * 256;
      int n = c >> 3, ch = c & 7;
      int gk = kc + ch * 8;
      bhR[i] = *(const uint4*)(BThi + (size_t)n * KPAD + gk);
      blR[i] = *(const uint4*)(BTlo + (size_t)n * KPAD + gk);
    }
  };

  auto write_st = [&]() {
    #pragma unroll
    for (int i = 0; i < 8; ++i) {
      int c = tid + i * 256;
      int r = c >> 4, k4 = (c & 15) << 2;
      float4 v = aR[i];
      ushort h0 = f2bf_rn(v.x), h1 = f2bf_rn(v.y), h2 = f2bf_rn(v.z), h3 = f2bf_rn(v.w);
      ushort l0 = f2bf_rn(v.x - bf2f(h0)), l1 = f2bf_rn(v.y - bf2f(h1));
      ushort l2 = f2bf_rn(v.z - bf2f(h2)), l3 = f2bf_rn(v.w - bf2f(h3));
      int chunk = k4 >> 3, sub = k4 & 4;
      int ad = r * 64 + ((chunk << 3) ^ ((r & 7) << 3)) + sub;
      *(ushort4*)(Ahi + ad) = make_ushort4(h0, h1, h2, h3);
      *(ushort4*)(Alo + ad) = make_ushort4(l0, l1, l2, l3);
    }
    #pragma unroll
    for (int i = 0; i < NB; ++i) {
      int c = tid + i * 256;
      int n = c >> 3, ch = c & 7;
      int ad = n * 64 + ((ch << 3) ^ ((n & 7) << 3));
      *(uint4*)(Bhi + ad) = bhR[i];
      *(uint4*)(Blo + ad) = blR[i];
    }
  };

  load_st(0);
  write_st();
  __syncthreads();

  #pragma unroll 1
  for (int s = 0; s < NS; ++s) {
    if (s + 1 < NS) load_st((s + 1) * BK);   // prefetch next tile into regs
    // ---- MFMA on current LDS contents: 2 k-subs of 32 ----
    #pragma unroll
    for (int ks = 0; ks < 2; ++ks) {
      bf16x8 ah[4], al[4], bh[NF], bl[NF];
      #pragma unroll
      for (int m = 0; m < 4; ++m) {
        int r = wm * 64 + m * 16 + lrow;
        int ad = r * 64 + (((ks * 4 + lg) << 3) ^ ((r & 7) << 3));
        ah[m] = *(const bf16x8*)(Ahi + ad);
        al[m] = *(const bf16x8*)(Alo + ad);
      }
      #pragma unroll
      for (int n = 0; n < NF; ++n) {
        int r = wn * (BN / 2) + n * 16 + lrow;
        int ad = r * 64 + (((ks * 4 + lg) << 3) ^ ((r & 7) << 3));
        bh[n] = *(const bf16x8*)(Bhi + ad);
        bl[n] = *(const bf16x8*)(Blo + ad);
      }
      #pragma unroll
      for (int m = 0; m < 4; ++m)
        #pragma unroll
        for (int n = 0; n < NF; ++n) {
          acc[m][n] = __builtin_amdgcn_mfma_f32_16x16x32_bf16(ah[m], bh[n], acc[m][n], 0, 0, 0);
          acc[m][n] = __builtin_amdgcn_mfma_f32_16x16x32_bf16(ah[m], bl[n], acc[m][n], 0, 0, 0);
          acc[m][n] = __builtin_amdgcn_mfma_f32_16x16x32_bf16(al[m], bh[n], acc[m][n], 0, 0, 0);
        }
    }
    if (s + 1 < NS) {
      __syncthreads();   // all waves done reading this LDS tile
      write_st();        // commit prefetched tile (vmcnt wait lands here)
      __syncthreads();
    }
  }

  // ---- epilogue: C/D layout col=lane&15, row=(lane>>4)*4+reg (verified) ----
  #pragma unroll
  for (int m = 0; m < 4; ++m)
    #pragma unroll
    for (int n = 0; n < NF; ++n) {
      int gcol = wn * (BN / 2) + n * 16 + lrow;
      float bb = bias[gcol];
      #pragma unroll
      for (int r = 0; r < 4; ++r) {
        int grow = row0 + wm * 64 + m * 16 + lg * 4 + r;
        if (grow < M) {
          float v = acc[m][n][r] + bb;
          if (RELU) v = fmaxf(v, 0.f);
          C[(size_t)grow * BN + gcol] = v;
        }
      }
    }
}

// ---------------- y0 = fp16(dinv * h0), row-major [N][64] ----------------
__global__ __launch_bounds__(256) void conv_y0_k(const float* __restrict__ h0,
                                                 const float* __restrict__ dinv,
                                                 uint2* __restrict__ y16) {
  int i = blockIdx.x * 256 + threadIdx.x;  // one float4 / uint2 per thread
  if (i >= N_NODES * 16) return;
  int node = i >> 4;
  float dv = dinv[node];
  float4 h4 = ((const float4*)h0)[i];
  y16[i] = make_uint2(f2h2(dv * h4.x, dv * h4.y), f2h2(dv * h4.z, dv * h4.w));
}

// ---------------- propagation: fp16 y-gather, weights folded ----------------
// y = dinv*z stored fp16 [N+1][64] (row 128B; row N_NODES is a zero pad row).
// Wave = one node: 16 lanes per edge-row (8B/lane); 8 gathers in flight.
template<bool OUT32>
__global__ __launch_bounds__(256) void prop_k(const uint2* __restrict__ yin,
                                              void* __restrict__ out,
                                              const float* __restrict__ h0,
                                              const float* __restrict__ dinv,
                                              const int* __restrict__ offs,
                                              const int* __restrict__ csr4) {
  int lane = threadIdx.x & 63;
  int wid = threadIdx.x >> 6;
  int node = (blockIdx.x << 2) + wid;
  if (node >= N_NODES) return;
  int grp = lane >> 4;   // edge slot within group of 4
  int lc = lane & 15;    // uint2 slot within 64-ch row

  float4 acc = make_float4(0.f, 0.f, 0.f, 0.f);
  int beg = offs[node], end = offs[node + 1];
  for (int e = beg; e < end; e += 64) {
    int s = (e + lane < end) ? csr4[e + lane] : N_NODES;  // pad -> zero row
    int cnt = min(64, end - e);
    for (int j = 0; j < cnt; j += 32) {
      int sr[8];
      uint2 g[8];
      #pragma unroll
      for (int q = 0; q < 8; ++q) sr[q] = __shfl(s, j + 4 * q + grp);
      #pragma unroll
      for (int q = 0; q < 8; ++q) g[q] = yin[(size_t)sr[q] * 16 + lc];
      #pragma unroll
      for (int q = 0; q < 8; ++q) {
        float2 a = h2f2(g[q].x), b = h2f2(g[q].y);
        acc.x += a.x; acc.y += a.y; acc.z += b.x; acc.w += b.y;
      }
    }
  }
  // merge the 4 group-partials (lane bits 4,5)
  #pragma unroll
  for (int off = 16; off <= 32; off <<= 1) {
    acc.x += __shfl_xor(acc.x, off);
    acc.y += __shfl_xor(acc.y, off);
    acc.z += __shfl_xor(acc.z, off);
    acc.w += __shfl_xor(acc.w, off);
  }
  if (grp == 0) {
    // self term
    uint2 gs = yin[(size_t)node * 16 + lc];
    float2 a = h2f2(gs.x), b = h2f2(gs.y);
    acc.x += a.x; acc.y += a.y; acc.z += b.x; acc.w += b.y;
    float dv = dinv[node];
    float4 h4 = ((const float4*)h0)[(size_t)node * 16 + lc];
    float4 z;
    z.x = 0.9f * dv * acc.x + 0.1f * h4.x;
    z.y = 0.9f * dv * acc.y + 0.1f * h4.y;
    z.z = 0.9f * dv * acc.z + 0.1f * h4.z;
    z.w = 0.9f * dv * acc.w + 0.1f * h4.w;
    if (OUT32) {
      ((float4*)out)[(size_t)node * 16 + lc] = z;
    } else {
      ((uint2*)out)[(size_t)node * 16 + lc] =
          make_uint2(f2h2(dv * z.x, dv * z.y), f2h2(dv * z.z, dv * z.w));
    }
  }
}

// ---------------- softmax over 64 classes, one wave per row ----------------
__global__ __launch_bounds__(256) void softmax_k(const float* __restrict__ z,
                                                 float* __restrict__ out) {
  int lane = threadIdx.x & 63;
  int row = (blockIdx.x * 256 + threadIdx.x) >> 6;
  if (row >= N_NODES) return;
  float v = z[(size_t)row * 64 + lane];
  float m = v;
  #pragma unroll
  for (int o = 32; o > 0; o >>= 1) m = fmaxf(m, __shfl_xor(m, o));
  float ev = __expf(v - m);
  float s = ev;
  #pragma unroll
  for (int o = 32; o > 0; o >>= 1) s += __shfl_xor(s, o);
  out[(size_t)row * 64 + lane] = ev / s;
}

extern "C" void kernel_launch(void* const* d_in, const int* in_sizes, int n_in,
                              void* d_out, int out_size, void* d_ws, size_t ws_size,
                              hipStream_t stream) {
  const float* x  = (const float*)d_in[0];
  const int*   ei = (const int*)d_in[1];
  const float* W1 = (const float*)d_in[2];
  const float* b1 = (const float*)d_in[3];
  const float* W2 = (const float*)d_in[4];
  const float* b2 = (const float*)d_in[5];
  const int* src = ei;
  const int* dst = ei + N_EDGES;

  char* w = (char*)d_ws;
  // Layout (bytes):
  //   [0, 12.8M)        csr4
  //   [12.8M, 64.0M)    H (gemm1 out / gemm2 in) -- dead after gemm2, overlaid:
  //       zA16 @12.8M (+pad row @25.6M), zB16 @25.7M (+pad row @38.5M),
  //       zF32 @38.6M (25.6M) -- and 'binned' @38.6M (setup-only)
  //   [64.5M, ...)      dinv, offs, bucket arrays, weight-prep buffers
  int*    csr4  = (int*)w;
  float*  H     = (float*)(w + 12800000);
  uint2*  zA16  = (uint2*)(w + 12800000);
  uint2*  zB16  = (uint2*)(w + 25700000);
  float*  zF32  = (float*)(w + 38600000);
  int*    binned = (int*)(w + 38600000);
  float*  dinv  = (float*)(w + 64500000);
  int*    offs  = (int*)(w + 65000000);
  int*    bucket_cnt  = (int*)(w + 66000000);   // 128 ints
  int*    bucket_base = (int*)(w + 66002048);   // 129 ints
  int*    bcur        = (int*)(w + 66004096);   // 128 ints
  ushort* w1thi = (ushort*)(w + 66500000);
  ushort* w1tlo = (ushort*)(w + 66700000);
  ushort* w2thi = (ushort*)(w + 66900000);
  ushort* w2tlo = (ushort*)(w + 67000000);
  float* h0 = (float*)d_out;  // fp32 [N][64]; dead once last layer reads it

  hipMemsetAsync(bucket_cnt, 0, 128 * 4, stream);

  // ---- CSR build (bucketed counting sort) ----
  bucket_count_k<<<512, 256, 0, stream>>>(dst, bucket_cnt);
  bucket_scan_k<<<1, 128, 0, stream>>>(bucket_cnt, bucket_base, bcur, offs);
  bin_scatter_k<<<N_EDGES / BIN_CHUNK, 256, 0, stream>>>(src, dst, bcur, binned);
  bucket_fill_k<<<NBUCK, 256, 0, stream>>>(binned, bucket_base, offs, dinv, csr4);

  // ---- MLP ----
  prep_wt_k<<<(128 * 512 + 255) / 256, 256, 0, stream>>>(W1, w1thi, w1tlo, 500, 128, 512);
  prep_wt_k<<<(64 * 128 + 255) / 256, 256, 0, stream>>>(W2, w2thi, w2tlo, 128, 64, 128);
  mfma_gemm_k<128, 500, 512, true><<<(N_NODES + 127) / 128, 256, 0, stream>>>(
      x, w1thi, w1tlo, b1, H, N_NODES);
  mfma_gemm_k<64, 128, 128, false><<<(N_NODES + 127) / 128, 256, 0, stream>>>(
      H, w2thi, w2tlo, b2, h0, N_NODES);

  // Zero the pad rows (index N_NODES) of both fp16 y buffers. MUST happen
  // after the GEMMs: zA16/zB16 overlay H and gemm1 would clobber the pads
  // (round 5's absmax=0.99 bug). prop_k never writes pad rows.
  hipMemsetAsync((char*)zA16 + (size_t)N_NODES * 128, 0, 128, stream);
  hipMemsetAsync((char*)zB16 + (size_t)N_NODES * 128, 0, 128, stream);

  conv_y0_k<<<(N_NODES * 16 + 255) / 256, 256, 0, stream>>>(h0, dinv, zA16);

  const uint2* zi = zA16;
  uint2* zo = zB16;
  for (int it = 0; it < K_LAYERS - 1; ++it) {
    prop_k<false><<<(N_NODES + 3) / 4, 256, 0, stream>>>(zi, (void*)zo, h0, dinv, offs, csr4);
    zi = zo;
    zo = (zo == zA16) ? zB16 : zA16;
  }
  prop_k<true><<<(N_NODES + 3) / 4, 256, 0, stream>>>(zi, (void*)zF32, h0, dinv, offs, csr4);

  softmax_k<<<(N_NODES * 64) / 256, 256, 0, stream>>>(zF32, (float*)d_out);
}

// Round 10
// 993.755 us; speedup vs baseline: 1.1287x; 1.1287x over previous
//
#include <hip/hip_runtime.h>
#include <hip/hip_bf16.h>
#include <hip/hip_fp16.h>

#define N_NODES   100000
#define N_EDGES   3200000
#define N_FEAT    500
#define HIDDEN    128
#define N_CLASSES 64
#define K_LAYERS  10
#define NBUCK     98          // ceil(N_NODES / 1024)

typedef __attribute__((ext_vector_type(4))) float f32x4;
typedef __attribute__((ext_vector_type(8))) _Float16 f16x8;

__device__ inline float2 h2f2(unsigned u) {
  __half2 h = *(__half2*)&u;
  return make_float2(__low2float(h), __high2float(h));
}
__device__ inline unsigned f2h2(float a, float b) {
  __half2 h = __floats2half2_rn(a, b);
  return *(unsigned*)&h;
}

// ============ CSR build via bucketed counting sort (no global scatter) ======
// Records packed as src | (dstLocal<<17); src < 2^17, dstLocal < 1024.

__global__ __launch_bounds__(256) void bucket_count_k(const int* __restrict__ dst,
                                                      int* __restrict__ bucket_cnt) {
  __shared__ int h[128];
  int t = threadIdx.x;
  if (t < 128) h[t] = 0;
  __syncthreads();
  for (int e = blockIdx.x * 256 + t; e < N_EDGES; e += gridDim.x * 256)
    atomicAdd(&h[dst[e] >> 10], 1);
  __syncthreads();
  if (t < 128 && h[t]) atomicAdd(&bucket_cnt[t], h[t]);
}

__global__ __launch_bounds__(128) void bucket_scan_k(const int* __restrict__ bucket_cnt,
                                                     int* __restrict__ bucket_base,
                                                     int* __restrict__ bcur,
                                                     int* __restrict__ offs) {
  __shared__ int sm[128];
  int t = threadIdx.x;
  int c = bucket_cnt[t];
  sm[t] = c;
  __syncthreads();
  for (int d = 1; d < 128; d <<= 1) {
    int v = (t >= d) ? sm[t - d] : 0;
    __syncthreads();
    sm[t] += v;
    __syncthreads();
  }
  int ex = sm[t] - c;  // exclusive prefix
  bucket_base[t] = ex;
  bcur[t] = ex;
  if (t == 127) bucket_base[128] = ex + c;  // == N_EDGES
  if (t == 0) offs[N_NODES] = N_EDGES;
}

#define BIN_CHUNK 12800   // 250 blocks * 12800 = 3.2M exactly
__global__ __launch_bounds__(256) void bin_scatter_k(const int* __restrict__ src,
                                                     const int* __restrict__ dst,
                                                     int* __restrict__ bcur,
                                                     int* __restrict__ binned) {
  __shared__ int h[128];
  __shared__ int hbase[128];
  int t = threadIdx.x;
  int e0 = blockIdx.x * BIN_CHUNK;
  int e1 = min(e0 + BIN_CHUNK, N_EDGES);
  if (t < 128) h[t] = 0;
  __syncthreads();
  for (int e = e0 + t; e < e1; e += 256) atomicAdd(&h[dst[e] >> 10], 1);
  __syncthreads();
  if (t < 128) {
    int c = h[t];
    hbase[t] = c ? atomicAdd(&bcur[t], c) : 0;
  }
  __syncthreads();
  if (t < 128) h[t] = 0;
  __syncthreads();
  for (int e = e0 + t; e < e1; e += 256) {
    int d = dst[e];
    int b = d >> 10;
    int pos = hbase[b] + atomicAdd(&h[b], 1);
    binned[pos] = (src[e] & 0x1FFFF) | ((d & 1023) << 17);
  }
}

__global__ __launch_bounds__(256) void bucket_fill_k(const int* __restrict__ binned,
                                                     const int* __restrict__ bucket_base,
                                                     int* __restrict__ offs,
                                                     float* __restrict__ dinv,
                                                     int* __restrict__ csr4) {
  __shared__ int cnt[1024];
  __shared__ int tsum[256];
  int b = blockIdx.x;
  int base = bucket_base[b];
  int nE = bucket_base[b + 1] - base;
  int node0 = b << 10;
  int nN = min(1024, N_NODES - node0);
  int t = threadIdx.x;
  #pragma unroll
  for (int i = 0; i < 4; ++i) cnt[t + i * 256] = 0;
  __syncthreads();
  for (int i = t; i < nE; i += 256) atomicAdd(&cnt[binned[base + i] >> 17], 1);
  __syncthreads();
  int c0 = cnt[4 * t], c1 = cnt[4 * t + 1], c2 = cnt[4 * t + 2], c3 = cnt[4 * t + 3];
  int s = c0 + c1 + c2 + c3;
  tsum[t] = s;
  __syncthreads();
  for (int d = 1; d < 256; d <<= 1) {
    int v = (t >= d) ? tsum[t - d] : 0;
    __syncthreads();
    tsum[t] += v;
    __syncthreads();
  }
  int run = tsum[t] - s;  // exclusive
  int p0 = run, p1 = run + c0, p2 = p1 + c1, p3 = p2 + c2;
  if (4 * t + 0 < nN) { offs[node0 + 4 * t + 0] = base + p0; dinv[node0 + 4 * t + 0] = rsqrtf(c0 + 1.f); }
  if (4 * t + 1 < nN) { offs[node0 + 4 * t + 1] = base + p1; dinv[node0 + 4 * t + 1] = rsqrtf(c1 + 1.f); }
  if (4 * t + 2 < nN) { offs[node0 + 4 * t + 2] = base + p2; dinv[node0 + 4 * t + 2] = rsqrtf(c2 + 1.f); }
  if (4 * t + 3 < nN) { offs[node0 + 4 * t + 3] = base + p3; dinv[node0 + 4 * t + 3] = rsqrtf(c3 + 1.f); }
  __syncthreads();
  cnt[4 * t] = p0; cnt[4 * t + 1] = p1; cnt[4 * t + 2] = p2; cnt[4 * t + 3] = p3;
  __syncthreads();
  for (int i = t; i < nE; i += 256) {
    int rec = binned[base + i];
    int p = base + atomicAdd(&cnt[rec >> 17], 1);
    csr4[p] = rec & 0x1FFFF;
  }
}

// ---------------- weight prep: fp16, pre-swizzled, K-step-chunked ------------
// Bsw[s*BN*64 + c*64 + ((X ^ (c&7))<<3) + e] = fp16(W[s*64 + X*8 + e][c]), 0 if k>=KTOT.
// Linear global_load_lds of a 16KB chunk then reproduces the XOR-swizzled LDS
// layout that the ds_read_b128 fragment reads expect (T21: both-sides swizzle).
__global__ void prep_wsw_k(const float* __restrict__ W, ushort* __restrict__ Bsw,
                           int KTOT, int BN, int KPAD) {
  int g = blockIdx.x * 256 + threadIdx.x;
  if (g >= BN * KPAD) return;
  int chunk = BN * 64;
  int s = g / chunk;
  int r = g - s * chunk;
  int c = r >> 6;
  int q = r & 63;
  int X = (q >> 3) ^ (c & 7);
  int e = q & 7;
  int k = s * 64 + X * 8 + e;
  float v = (k < KTOT) ? W[(size_t)k * BN + c] : 0.f;
  _Float16 hv = (_Float16)v;
  Bsw[g] = *(ushort*)&hv;
}

// ---------------- fp16 MFMA GEMM core: C[M x BN] = A[M x KTOT] @ B + bias ---
// Templated __device__ core (device-pass only; avoids the template-__global__
// + global_load_lds stub-emission bug from round 9). 4 waves; wave w owns rows
// [row0+w*32, +32) x ALL BN cols. A: direct global->register fragments. B:
// double-buffered LDS via linear global_load_lds from pre-swizzled Bsw; one
// vmcnt(0)+barrier per K-step. ds_read swizzle: ushort = c*64 + ((X^(c&7))<<3).
template<int BN, int KTOT, int KPAD, bool RELU, bool A16, bool C16>
__device__ __forceinline__ void gemm_core(const void* Ain, const ushort* Bsw,
                                          const float* bias, void* Cout, int M) {
  constexpr int BK = 64;
  constexpr int NS = KPAD / BK;
  constexpr int NF = BN / 16;                  // n-frags per wave
  constexpr int CHUNK = BN * BK;               // ushorts per K-step
  constexpr int NL = CHUNK * 2 / (16 * 256);   // global_load_lds insts/thread
  __shared__ __align__(16) ushort Bl[2][CHUNK];

  int tid = threadIdx.x;
  int lane = tid & 63, w = tid >> 6;
  int lrow = lane & 15, lg = lane >> 4;
  int row0 = blockIdx.x * 128 + w * 32;

  const float* A32 = (const float*)Ain;
  const ushort* Ah = (const ushort*)Ain;

  f32x4 acc[2][NF];
  #pragma unroll
  for (int m = 0; m < 2; ++m)
    #pragma unroll
    for (int n = 0; n < NF; ++n) acc[m][n] = (f32x4){0.f, 0.f, 0.f, 0.f};

  // stage step s into buffer buf (linear, 16B per lane per inst)
  #define STAGE(s, buf)                                                   \
    {                                                                     \
      const ushort* gp = Bsw + (size_t)(s) * CHUNK;                       \
      _Pragma("unroll")                                                   \
      for (int i = 0; i < NL; ++i) {                                      \
        int o = (tid + i * 256) * 8;                                      \
        __builtin_amdgcn_global_load_lds(gp + o, &Bl[buf][o], 16, 0, 0);  \
      }                                                                   \
    }

  STAGE(0, 0);
  asm volatile("s_waitcnt vmcnt(0)" ::: "memory");
  __syncthreads();

  #pragma unroll 1
  for (int s = 0; s < NS; ++s) {
    int cur = s & 1;
    if (s + 1 < NS) STAGE(s + 1, cur ^ 1);
    int kc = s * BK;
    #pragma unroll
    for (int ks = 0; ks < 2; ++ks) {
      f16x8 af[2];
      #pragma unroll
      for (int m = 0; m < 2; ++m) {
        int r = row0 + m * 16 + lrow;
        int rc = r < M ? r : M - 1;            // clamp; garbage rows unused
        int k0 = kc + ks * 32 + lg * 8;
        if (A16) {
          af[m] = *(const f16x8*)(Ah + (size_t)rc * KPAD + k0);
        } else {
          const float* ap = A32 + (size_t)rc * KTOT + k0;
          f16x8 h;
          if (k0 + 7 < KTOT) {
            float4 f0 = *(const float4*)ap;
            float4 f1 = *(const float4*)(ap + 4);
            h[0] = (_Float16)f0.x; h[1] = (_Float16)f0.y;
            h[2] = (_Float16)f0.z; h[3] = (_Float16)f0.w;
            h[4] = (_Float16)f1.x; h[5] = (_Float16)f1.y;
            h[6] = (_Float16)f1.z; h[7] = (_Float16)f1.w;
          } else {
            // K-tail: B rows for k>=KTOT are zero, so values only matter
            // for k<KTOT slots; guard loads to stay in-bounds.
            #pragma unroll
            for (int e = 0; e < 8; ++e)
              h[e] = (_Float16)((k0 + e < KTOT) ? ap[e] : 0.f);
          }
          af[m] = h;
        }
      }
      #pragma unroll
      for (int n = 0; n < NF; ++n) {
        int c = n * 16 + lrow;
        int ad = c * 64 + ((((ks << 2) + lg) ^ (c & 7)) << 3);  // ushort idx
        f16x8 bf = *(const f16x8*)(&Bl[cur][ad]);
        #pragma unroll
        for (int m = 0; m < 2; ++m)
          acc[m][n] = __builtin_amdgcn_mfma_f32_16x16x32_f16(af[m], bf, acc[m][n], 0, 0, 0);
      }
    }
    asm volatile("s_waitcnt vmcnt(0)" ::: "memory");
    __syncthreads();
  }
  #undef STAGE

  // epilogue: C/D layout col=lane&15, row=(lane>>4)*4+reg (verified)
  #pragma unroll
  for (int m = 0; m < 2; ++m)
    #pragma unroll
    for (int n = 0; n < NF; ++n) {
      int c = n * 16 + lrow;
      float bb = bias[c];
      #pragma unroll
      for (int r4 = 0; r4 < 4; ++r4) {
        int grow = row0 + m * 16 + lg * 4 + r4;
        if (grow < M) {
          float v = acc[m][n][r4] + bb;
          if (RELU) v = fmaxf(v, 0.f);
          if (C16) {
            _Float16 hv = (_Float16)v;
            ((ushort*)Cout)[(size_t)grow * BN + c] = *(ushort*)&hv;
          } else {
            ((float*)Cout)[(size_t)grow * BN + c] = v;
          }
        }
      }
    }
}

// Non-template wrappers: ordinary host stubs, no template-stub emission issue.
__global__ __launch_bounds__(256, 2) void gemm1_k(const float* __restrict__ A,
                                                  const ushort* __restrict__ Bsw,
                                                  const float* __restrict__ bias,
                                                  ushort* __restrict__ C, int M) {
  gemm_core<128, 500, 512, true, false, true>(A, Bsw, bias, C, M);
}
__global__ __launch_bounds__(256, 2) void gemm2_k(const ushort* __restrict__ A,
                                                  const ushort* __restrict__ Bsw,
                                                  const float* __restrict__ bias,
                                                  float* __restrict__ C, int M) {
  gemm_core<64, 128, 128, false, true, false>(A, Bsw, bias, C, M);
}

// ---------------- y0 = fp16(dinv * h0), row-major [N][64] ----------------
__global__ __launch_bounds__(256) void conv_y0_k(const float* __restrict__ h0,
                                                 const float* __restrict__ dinv,
                                                 uint2* __restrict__ y16) {
  int i = blockIdx.x * 256 + threadIdx.x;  // one float4 / uint2 per thread
  if (i >= N_NODES * 16) return;
  int node = i >> 4;
  float dv = dinv[node];
  float4 h4 = ((const float4*)h0)[i];
  y16[i] = make_uint2(f2h2(dv * h4.x, dv * h4.y), f2h2(dv * h4.z, dv * h4.w));
}

// ---------------- propagation: fp16 y-gather, weights folded ----------------
// y = dinv*z stored fp16 [N+1][64] (row 128B; row N_NODES is a zero pad row).
// Wave = one node: 16 lanes per edge-row (8B/lane); 8 gathers in flight.
template<bool OUT32>
__global__ __launch_bounds__(256) void prop_k(const uint2* __restrict__ yin,
                                              void* __restrict__ out,
                                              const float* __restrict__ h0,
                                              const float* __restrict__ dinv,
                                              const int* __restrict__ offs,
                                              const int* __restrict__ csr4) {
  int lane = threadIdx.x & 63;
  int wid = threadIdx.x >> 6;
  int node = (blockIdx.x << 2) + wid;
  if (node >= N_NODES) return;
  int grp = lane >> 4;   // edge slot within group of 4
  int lc = lane & 15;    // uint2 slot within 64-ch row

  float4 acc = make_float4(0.f, 0.f, 0.f, 0.f);
  int beg = offs[node], end = offs[node + 1];
  for (int e = beg; e < end; e += 64) {
    int s = (e + lane < end) ? csr4[e + lane] : N_NODES;  // pad -> zero row
    int cnt = min(64, end - e);
    for (int j = 0; j < cnt; j += 32) {
      int sr[8];
      uint2 g[8];
      #pragma unroll
      for (int q = 0; q < 8; ++q) sr[q] = __shfl(s, j + 4 * q + grp);
      #pragma unroll
      for (int q = 0; q < 8; ++q) g[q] = yin[(size_t)sr[q] * 16 + lc];
      #pragma unroll
      for (int q = 0; q < 8; ++q) {
        float2 a = h2f2(g[q].x), b = h2f2(g[q].y);
        acc.x += a.x; acc.y += a.y; acc.z += b.x; acc.w += b.y;
      }
    }
  }
  // merge the 4 group-partials (lane bits 4,5)
  #pragma unroll
  for (int off = 16; off <= 32; off <<= 1) {
    acc.x += __shfl_xor(acc.x, off);
    acc.y += __shfl_xor(acc.y, off);
    acc.z += __shfl_xor(acc.z, off);
    acc.w += __shfl_xor(acc.w, off);
  }
  if (grp == 0) {
    // self term
    uint2 gs = yin[(size_t)node * 16 + lc];
    float2 a = h2f2(gs.x), b = h2f2(gs.y);
    acc.x += a.x; acc.y += a.y; acc.z += b.x; acc.w += b.y;
    float dv = dinv[node];
    float4 h4 = ((const float4*)h0)[(size_t)node * 16 + lc];
    float4 z;
    z.x = 0.9f * dv * acc.x + 0.1f * h4.x;
    z.y = 0.9f * dv * acc.y + 0.1f * h4.y;
    z.z = 0.9f * dv * acc.z + 0.1f * h4.z;
    z.w = 0.9f * dv * acc.w + 0.1f * h4.w;
    if (OUT32) {
      ((float4*)out)[(size_t)node * 16 + lc] = z;
    } else {
      ((uint2*)out)[(size_t)node * 16 + lc] =
          make_uint2(f2h2(dv * z.x, dv * z.y), f2h2(dv * z.z, dv * z.w));
    }
  }
}

// ---------------- softmax over 64 classes, one wave per row ----------------
__global__ __launch_bounds__(256) void softmax_k(const float* __restrict__ z,
                                                 float* __restrict__ out) {
  int lane = threadIdx.x & 63;
  int row = (blockIdx.x * 256 + threadIdx.x) >> 6;
  if (row >= N_NODES) return;
  float v = z[(size_t)row * 64 + lane];
  float m = v;
  #pragma unroll
  for (int o = 32; o > 0; o >>= 1) m = fmaxf(m, __shfl_xor(m, o));
  float ev = __expf(v - m);
  float s = ev;
  #pragma unroll
  for (int o = 32; o > 0; o >>= 1) s += __shfl_xor(s, o);
  out[(size_t)row * 64 + lane] = ev / s;
}

extern "C" void kernel_launch(void* const* d_in, const int* in_sizes, int n_in,
                              void* d_out, int out_size, void* d_ws, size_t ws_size,
                              hipStream_t stream) {
  const float* x  = (const float*)d_in[0];
  const int*   ei = (const int*)d_in[1];
  const float* W1 = (const float*)d_in[2];
  const float* b1 = (const float*)d_in[3];
  const float* W2 = (const float*)d_in[4];
  const float* b2 = (const float*)d_in[5];
  const int* src = ei;
  const int* dst = ei + N_EDGES;

  char* w = (char*)d_ws;
  // Layout (bytes):
  //   [0, 12.8M)        csr4
  //   [12.8M, 38.4M)    H fp16 (gemm1 out / gemm2 in) -- dead after gemm2;
  //       overlaid: zA16 @12.8M (+pad row), zB16 @25.7M (+pad row)
  //   [38.6M, 64.2M)    zF32 -- overlaid with 'binned' (setup-only)
  //   [64.5M, ...)      dinv, offs, bucket arrays, swizzled fp16 weights
  int*    csr4  = (int*)w;
  ushort* H     = (ushort*)(w + 12800000);
  uint2*  zA16  = (uint2*)(w + 12800000);
  uint2*  zB16  = (uint2*)(w + 25700000);
  float*  zF32  = (float*)(w + 38600000);
  int*    binned = (int*)(w + 38600000);
  float*  dinv  = (float*)(w + 64500000);
  int*    offs  = (int*)(w + 65000000);
  int*    bucket_cnt  = (int*)(w + 66000000);   // 128 ints
  int*    bucket_base = (int*)(w + 66002048);   // 129 ints
  int*    bcur        = (int*)(w + 66004096);   // 128 ints
  ushort* w1sw  = (ushort*)(w + 66500000);      // 128*512 ushorts = 128 KB
  ushort* w2sw  = (ushort*)(w + 66700000);      // 64*128 ushorts = 16 KB
  float* h0 = (float*)d_out;  // fp32 [N][64]; dead once last layer reads it

  hipMemsetAsync(bucket_cnt, 0, 128 * 4, stream);

  // ---- CSR build (bucketed counting sort) ----
  bucket_count_k<<<512, 256, 0, stream>>>(dst, bucket_cnt);
  bucket_scan_k<<<1, 128, 0, stream>>>(bucket_cnt, bucket_base, bcur, offs);
  bin_scatter_k<<<N_EDGES / BIN_CHUNK, 256, 0, stream>>>(src, dst, bcur, binned);
  bucket_fill_k<<<NBUCK, 256, 0, stream>>>(binned, bucket_base, offs, dinv, csr4);

  // ---- MLP (fp16 single-MFMA) ----
  prep_wsw_k<<<(128 * 512 + 255) / 256, 256, 0, stream>>>(W1, w1sw, 500, 128, 512);
  prep_wsw_k<<<(64 * 128 + 255) / 256, 256, 0, stream>>>(W2, w2sw, 128, 64, 128);
  gemm1_k<<<(N_NODES + 127) / 128, 256, 0, stream>>>(x, w1sw, b1, H, N_NODES);
  gemm2_k<<<(N_NODES + 127) / 128, 256, 0, stream>>>(H, w2sw, b2, h0, N_NODES);

  // Zero the pad rows (index N_NODES) of both fp16 y buffers. MUST happen
  // after the GEMMs: zA16/zB16 overlay H and gemm1 would clobber the pads
  // (round 5's absmax=0.99 bug). prop_k never writes pad rows.
  hipMemsetAsync((char*)zA16 + (size_t)N_NODES * 128, 0, 128, stream);
  hipMemsetAsync((char*)zB16 + (size_t)N_NODES * 128, 0, 128, stream);

  conv_y0_k<<<(N_NODES * 16 + 255) / 256, 256, 0, stream>>>(h0, dinv, zA16);

  const uint2* zi = zA16;
  uint2* zo = zB16;
  for (int it = 0; it < K_LAYERS - 1; ++it) {
    prop_k<false><<<(N_NODES + 3) / 4, 256, 0, stream>>>(zi, (void*)zo, h0, dinv, offs, csr4);
    zi = zo;
    zo = (zo == zA16) ? zB16 : zA16;
  }
  prop_k<true><<<(N_NODES + 3) / 4, 256, 0, stream>>>(zi, (void*)zF32, h0, dinv, offs, csr4);

  softmax_k<<<(N_NODES * 64) / 256, 256, 0, stream>>>(zF32, (float*)d_out);
}